// Round 6
// baseline (6931.335 us; speedup 1.0000x reference)
//
#include <hip/hip_runtime.h>
#include <hip/hip_bf16.h>
#include <stdint.h>

#define S 2048
#define D 64
#define BH 32
#define NROWS (BH * S)              // 65536
#define CTX_ELEMS (NROWS * D)
#define BMC 128                     // rows per consumer tile
#define NTILES (NROWS / BMC)        // 512

typedef __attribute__((ext_vector_type(8))) __bf16 bf16x8;
typedef __attribute__((ext_vector_type(4))) float f32x4;
typedef __attribute__((ext_vector_type(4))) int   i32x4;

// One kernel, two block roles.
//  - blocks [NTILES, NTILES+NROWS): PRODUCER — one mask row: attn row +
//    packed bits (into ctx region, tile-local aliasing), then release flag.
//  - blocks [0, NTILES): CONSUMER — acquire-spin on tile flag (128 rows),
//    then ctx = inv * (bits @ V) via MFMA (R3-proven body). Runs UNDER the
//    producer stream. Deadlock-free: 512 consumer blocks can never occupy
//    all CU slots, so producers always progress (device-scope atomics, G16).
__global__ __launch_bounds__(256) void k_all(const int* __restrict__ mask,
                                             const float* __restrict__ V,
                                             float* __restrict__ ctx,
                                             float* __restrict__ attn,
                                             int* __restrict__ flags) {
  const int t = threadIdx.x;

  __shared__ uint32_t pk[BMC * 65];   // consumer: byte stride 260 -> bank stride 1
  __shared__ float invs[BMC];
  __shared__ int wsum[4];
  __shared__ unsigned char bts[256];

  if (blockIdx.x >= NTILES) {
    // ================= PRODUCER: one mask row =================
    const int r = blockIdx.x - NTILES;
    const long base = (long)r * S + t * 8;

    const i32x4 m0 = __builtin_nontemporal_load((const i32x4*)(mask + base));
    const i32x4 m1 = __builtin_nontemporal_load((const i32x4*)(mask + base + 4));
    int v[8] = {m0[0], m0[1], m0[2], m0[3], m1[0], m1[1], m1[2], m1[3]};

    unsigned byte = 0;
    int cnt = 0;
#pragma unroll
    for (int j = 0; j < 8; ++j) {
      unsigned u = (v[j] == 0) ? 1u : 0u;   // 1 = unmasked
      byte |= u << j;
      cnt += (int)u;
    }
#pragma unroll
    for (int off = 32; off > 0; off >>= 1) cnt += __shfl_down(cnt, off, 64);

    bts[t] = (unsigned char)byte;
    if ((t & 63) == 0) wsum[t >> 6] = cnt;
    __syncthreads();

    const int total = wsum[0] + wsum[1] + wsum[2] + wsum[3];
    const float inv = (total > 0) ? (1.0f / (float)total) : 0.0f;

    f32x4 a0, a1;
    a0[0] = (byte & 1u)   ? inv : 0.0f;
    a0[1] = (byte & 2u)   ? inv : 0.0f;
    a0[2] = (byte & 4u)   ? inv : 0.0f;
    a0[3] = (byte & 8u)   ? inv : 0.0f;
    a1[0] = (byte & 16u)  ? inv : 0.0f;
    a1[1] = (byte & 32u)  ? inv : 0.0f;
    a1[2] = (byte & 64u)  ? inv : 0.0f;
    a1[3] = (byte & 128u) ? inv : 0.0f;
    __builtin_nontemporal_store(a0, (f32x4*)(attn + base));
    __builtin_nontemporal_store(a1, (f32x4*)(attn + base + 4));

    if (t < 64) {
      uint32_t w = (uint32_t)bts[4 * t]
                 | ((uint32_t)bts[4 * t + 1] << 8)
                 | ((uint32_t)bts[4 * t + 2] << 16)
                 | ((uint32_t)bts[4 * t + 3] << 24);
      ((uint32_t*)ctx)[(long)r * 64 + t] = w;   // packed bits, tile-local alias
    }

    __syncthreads();                            // all stores drained (vmcnt 0)
    if (t == 0) {
      __threadfence();                          // device-scope release
      __hip_atomic_fetch_add(&flags[r >> 7], 1, __ATOMIC_RELEASE,
                             __HIP_MEMORY_SCOPE_AGENT);
    }
    return;
  }

  // ================= CONSUMER: one 128-row tile =================
  // XCD swizzle: each XCD owns 4 whole (b,h) -> V panel (512KB) L2-resident
  const int flat = blockIdx.x;
  const int wid = (flat & 7) * (NTILES / 8) + (flat >> 3);
  const int qt = wid & 15;
  const int bh = wid >> 4;

  const int lane = t & 63;
  const int w = t >> 6;               // wave 0..3
  const int l15 = lane & 15;
  const int lk = lane >> 4;           // 0..3

  if (t == 0) {
    while (__hip_atomic_load(&flags[wid], __ATOMIC_ACQUIRE,
                             __HIP_MEMORY_SCOPE_AGENT) != BMC)
      __builtin_amdgcn_s_sleep(8);
  }
  __syncthreads();                    // acquire (L1 invalidated) visible to block

  const uint32_t* packed = (const uint32_t*)ctx;
  const long R0 = (long)bh * S + (long)qt * BMC;

  for (int i = t; i < BMC * 64; i += 256)
    pk[(i >> 6) * 65 + (i & 63)] = packed[(R0 + (i >> 6)) * 64 + (i & 63)];
  __syncthreads();

  if (t < BMC) {
    int c = 0;
#pragma unroll
    for (int i = 0; i < 64; ++i) c += __popc(pk[t * 65 + i]);
    invs[t] = (c > 0) ? (1.0f / (float)c) : 0.0f;
  }
  __syncthreads();

  const uint8_t* pkb = (const uint8_t*)pk;
  const uint8_t* aptr0 = pkb + (w * 32 + l15) * 260;        // mt=0 row
  const uint8_t* aptr1 = pkb + (w * 32 + 16 + l15) * 260;   // mt=1 row
  const float* vf0 = V + (long)bh * S * D + (long)lk * 8 * D + l15;

  f32x4 acc[2][4];
#pragma unroll
  for (int a = 0; a < 2; ++a)
#pragma unroll
    for (int b = 0; b < 4; ++b) acc[a][b] = f32x4{0.f, 0.f, 0.f, 0.f};

  float cur[32], nxt[32];

  auto LOADB = [&](float* dst, int kk) {
    const float* vp = vf0 + (long)kk * 32 * D;
#pragma unroll
    for (int n4 = 0; n4 < 4; ++n4)
#pragma unroll
      for (int j = 0; j < 8; ++j)
        dst[n4 * 8 + j] = vp[j * D + n4 * 16];
  };

  auto COMPUTE = [&](const float* buf, int kk) {
    bf16x8 bf[4];
#pragma unroll
    for (int n4 = 0; n4 < 4; ++n4) {
      bf16x8 x;
#pragma unroll
      for (int j = 0; j < 8; ++j) x[j] = (__bf16)buf[n4 * 8 + j];
      bf[n4] = x;
    }
    const uint32_t by0 = aptr0[kk * 4 + lk];
    const uint32_t by1 = aptr1[kk * 4 + lk];
    union { uint32_t u[4]; bf16x8 v; } a0, a1;
#pragma unroll
    for (int p = 0; p < 4; ++p) {
      a0.u[p] = (((by0 >> (2 * p)) & 1u) ? 0x3F80u : 0u)
              | (((by0 >> (2 * p + 1)) & 1u) ? 0x3F800000u : 0u);
      a1.u[p] = (((by1 >> (2 * p)) & 1u) ? 0x3F80u : 0u)
              | (((by1 >> (2 * p + 1)) & 1u) ? 0x3F800000u : 0u);
    }
#pragma unroll
    for (int n4 = 0; n4 < 4; ++n4) {
      acc[0][n4] = __builtin_amdgcn_mfma_f32_16x16x32_bf16(a0.v, bf[n4], acc[0][n4], 0, 0, 0);
      acc[1][n4] = __builtin_amdgcn_mfma_f32_16x16x32_bf16(a1.v, bf[n4], acc[1][n4], 0, 0, 0);
    }
  };

  LOADB(cur, 0);
#pragma unroll 1
  for (int kk = 0; kk < S / 32; kk += 2) {
    LOADB(nxt, kk + 1);
    COMPUTE(cur, kk);
    if (kk + 2 < S / 32) LOADB(cur, kk + 2);
    COMPUTE(nxt, kk + 1);
  }

  // epilogue: C/D layout col=l15, row=lk*4+ri (m89-verified)
#pragma unroll
  for (int mt = 0; mt < 2; ++mt) {
#pragma unroll
    for (int ri = 0; ri < 4; ++ri) {
      const int rloc = w * 32 + mt * 16 + lk * 4 + ri;
      const float iv = invs[rloc];
      const long orow = R0 + rloc;
#pragma unroll
      for (int n4 = 0; n4 < 4; ++n4)
        ctx[orow * D + n4 * 16 + l15] = acc[mt][n4][ri] * iv;
    }
  }
}

extern "C" void kernel_launch(void* const* d_in, const int* in_sizes, int n_in,
                              void* d_out, int out_size, void* d_ws, size_t ws_size,
                              hipStream_t stream) {
  (void)in_sizes; (void)n_in; (void)out_size; (void)ws_size;
  const float* V = (const float*)d_in[2];           // Q,K provably unused (mask overwrites all scores)
  const int* mask = (const int*)d_in[3];
  float* ctx = (float*)d_out;                       // output 0: [B,H,S,D]
  float* attn = (float*)d_out + (size_t)CTX_ELEMS;  // output 1: [B,H,S,S]
  int* flags = (int*)d_ws;                          // NTILES ints

  hipMemsetAsync(flags, 0, NTILES * sizeof(int), stream);
  k_all<<<NTILES + NROWS, 256, 0, stream>>>(mask, V, ctx, attn, flags);
}

// Round 7
// 245.301 us; speedup vs baseline: 28.2564x; 28.2564x over previous
//
#include <hip/hip_runtime.h>
#include <hip/hip_bf16.h>
#include <stdint.h>

#define S 2048
#define D 64
#define BH 32
#define NROWS (BH * S)              // 65536
#define CTX_ELEMS (NROWS * D)
#define NVTB 512                    // VT rider blocks in the stream kernel
#define VT_BYTES ((size_t)BH * 64 * 64 * 32 * 2)   // 8.4 MB tiled bf16 V^T

typedef __attribute__((ext_vector_type(8))) __bf16 bf16x8;
typedef __attribute__((ext_vector_type(4))) float f32x4;
typedef __attribute__((ext_vector_type(4))) int   i32x4;

// VT32 layout: VT32[bh][kk][c][k']  (kk = k/32, c = V column 0..63, k' = k%32)
// -> B-fragment for MFMA step kk is one bf16x8 at ((bh*64+kk)*64+c)*32 + lk*8;
//    a wave's 64 lanes (c=n4*16+l15 x lk) cover a CONTIGUOUS 1KB range.

// ---------- Kernel 1: mask -> attn + packed bits, with VT riders ----------
// blocks [0, NVTB): transpose V into VT32 (independent, rides the stream).
// blocks [NVTB, NVTB+NROWS): R1-proven one-mask-row body.
__global__ __launch_bounds__(256) void k_mask(const int* __restrict__ mask,
                                              const float* __restrict__ V,
                                              float* __restrict__ attn,
                                              uint32_t* __restrict__ packed,
                                              __bf16* __restrict__ VT,
                                              int use_vt) {
  const int t = threadIdx.x;

  if (blockIdx.x < NVTB) {
    if (!use_vt) return;
    // ---- VT rider: block b covers bh = b>>4, kk in [ (b&15)*4, +4 ) ----
    const int bh = blockIdx.x >> 4;
    const int kk0 = (blockIdx.x & 15) * 4;
    const int c = t >> 2;             // 0..63
    const int g = t & 3;              // 0..3 (8 k' each)
#pragma unroll
    for (int s = 0; s < 4; ++s) {
      const int kk = kk0 + s;
      const float* vp = V + ((long)bh * S + kk * 32 + g * 8) * D + c;
      bf16x8 o;
#pragma unroll
      for (int j = 0; j < 8; ++j) o[j] = (__bf16)vp[(long)j * D];
      // store: addr = ((bh*64+kk)*64 + c)*32 + g*8 ; wave-contiguous 1KB
      *reinterpret_cast<bf16x8*>(VT + (((long)bh * 64 + kk) * 64 + c) * 32 + g * 8) = o;
    }
    return;
  }

  // ---- mask row body (R1/R3-proven) ----
  const int r = blockIdx.x - NVTB;
  const long base = (long)r * S + t * 8;

  const i32x4 m0 = __builtin_nontemporal_load((const i32x4*)(mask + base));
  const i32x4 m1 = __builtin_nontemporal_load((const i32x4*)(mask + base + 4));
  int v[8] = {m0[0], m0[1], m0[2], m0[3], m1[0], m1[1], m1[2], m1[3]};

  unsigned byte = 0;
  int cnt = 0;
#pragma unroll
  for (int j = 0; j < 8; ++j) {
    unsigned u = (v[j] == 0) ? 1u : 0u;   // 1 = unmasked
    byte |= u << j;
    cnt += (int)u;
  }
#pragma unroll
  for (int off = 32; off > 0; off >>= 1) cnt += __shfl_down(cnt, off, 64);

  __shared__ int wsum[4];
  __shared__ unsigned char bts[256];
  bts[t] = (unsigned char)byte;
  if ((t & 63) == 0) wsum[t >> 6] = cnt;
  __syncthreads();

  const int total = wsum[0] + wsum[1] + wsum[2] + wsum[3];
  const float inv = (total > 0) ? (1.0f / (float)total) : 0.0f;

  f32x4 a0, a1;
  a0[0] = (byte & 1u)   ? inv : 0.0f;
  a0[1] = (byte & 2u)   ? inv : 0.0f;
  a0[2] = (byte & 4u)   ? inv : 0.0f;
  a0[3] = (byte & 8u)   ? inv : 0.0f;
  a1[0] = (byte & 16u)  ? inv : 0.0f;
  a1[1] = (byte & 32u)  ? inv : 0.0f;
  a1[2] = (byte & 64u)  ? inv : 0.0f;
  a1[3] = (byte & 128u) ? inv : 0.0f;
  __builtin_nontemporal_store(a0, (f32x4*)(attn + base));
  __builtin_nontemporal_store(a1, (f32x4*)(attn + base + 4));

  if (t < 64) {
    uint32_t w = (uint32_t)bts[4 * t]
               | ((uint32_t)bts[4 * t + 1] << 8)
               | ((uint32_t)bts[4 * t + 2] << 16)
               | ((uint32_t)bts[4 * t + 3] << 24);
    packed[(long)r * 64 + t] = w;
  }
}

// ---------- Kernel 2: ctx = inv * (bits @ V) ----------
// 512 blocks x 128 thr (2 waves). Wave M=64 (4 m-tiles), N=64. B-frags from
// VT32 (one 1KB-contiguous wave load per n4) or f32-gather fallback. 2-deep
// software pipeline; packed bits in LDS (byte stride 260, conflict-free).
#define BMC 128
template<bool USE_VT>
__global__ __launch_bounds__(128) void k_ctx(const uint32_t* __restrict__ packed,
                                             const float* __restrict__ V,
                                             const __bf16* __restrict__ VT,
                                             float* __restrict__ ctx) {
  // XCD swizzle: each XCD owns 4 whole (b,h) -> VT panel (256KB) L2-resident
  const int flat = blockIdx.x;
  const int wid = (flat & 7) * ((NROWS / BMC) / 8) + (flat >> 3);
  const int qt = wid & 15;
  const int bh = wid >> 4;

  const int t = threadIdx.x;
  const int lane = t & 63;
  const int w = t >> 6;               // wave 0..1, rows [w*64, w*64+64)
  const int l15 = lane & 15;
  const int lk = lane >> 4;           // 0..3

  __shared__ uint32_t pk[BMC * 65];   // byte stride 260 -> bank stride 1
  __shared__ float invs[BMC];

  const long R0 = (long)bh * S + (long)qt * BMC;

  for (int i = t; i < BMC * 64; i += 128)
    pk[(i >> 6) * 65 + (i & 63)] = packed[(R0 + (i >> 6)) * 64 + (i & 63)];
  __syncthreads();

  {
    int c = 0;
#pragma unroll
    for (int i = 0; i < 64; ++i) c += __popc(pk[t * 65 + i]);
    invs[t] = (c > 0) ? (1.0f / (float)c) : 0.0f;
  }
  __syncthreads();

  const uint8_t* pkb = (const uint8_t*)pk;
  const uint8_t* ap[4];
#pragma unroll
  for (int mt = 0; mt < 4; ++mt)
    ap[mt] = pkb + (w * 64 + mt * 16 + l15) * 260 + lk;
  const __bf16* vt0 = VT + ((long)bh * 64) * 64 * 32 + (long)l15 * 32 + lk * 8;
  const float* vf0 = V + (long)bh * S * D + (long)lk * 8 * D + l15;

  f32x4 acc[4][4];
#pragma unroll
  for (int a = 0; a < 4; ++a)
#pragma unroll
    for (int b = 0; b < 4; ++b) acc[a][b] = f32x4{0.f, 0.f, 0.f, 0.f};

  auto LOADB = [&](bf16x8* dst, uint32_t* by, int kk) {
    if (USE_VT) {
#pragma unroll
      for (int n4 = 0; n4 < 4; ++n4)
        dst[n4] = *reinterpret_cast<const bf16x8*>(vt0 + ((long)kk * 64 + n4 * 16) * 32);
    } else {
      const float* vp = vf0 + (long)kk * 32 * D;
#pragma unroll
      for (int n4 = 0; n4 < 4; ++n4) {
        bf16x8 x;
#pragma unroll
        for (int j = 0; j < 8; ++j) x[j] = (__bf16)vp[j * D + n4 * 16];
        dst[n4] = x;
      }
    }
#pragma unroll
    for (int mt = 0; mt < 4; ++mt) by[mt] = ap[mt][kk * 4];
  };

  auto COMPUTE = [&](const bf16x8* bf, const uint32_t* by) {
#pragma unroll
    for (int mt = 0; mt < 4; ++mt) {
      union { uint32_t u[4]; bf16x8 v; } am;
#pragma unroll
      for (int p = 0; p < 4; ++p) {
        am.u[p] = (((by[mt] >> (2 * p)) & 1u) ? 0x3F80u : 0u)
                | (((by[mt] >> (2 * p + 1)) & 1u) ? 0x3F800000u : 0u);
      }
#pragma unroll
      for (int n4 = 0; n4 < 4; ++n4)
        acc[mt][n4] = __builtin_amdgcn_mfma_f32_16x16x32_bf16(am.v, bf[n4], acc[mt][n4], 0, 0, 0);
    }
  };

  bf16x8 bA[4], bB[4];
  uint32_t byA[4], byB[4];
  LOADB(bA, byA, 0);
#pragma unroll 1
  for (int kk = 0; kk < S / 32; kk += 2) {
    LOADB(bB, byB, kk + 1);
    COMPUTE(bA, byA);
    if (kk + 2 < S / 32) LOADB(bA, byA, kk + 2);
    COMPUTE(bB, byB);
  }

  // epilogue: C/D layout col=l15, row=lk*4+ri (m89-verified)
#pragma unroll
  for (int mt = 0; mt < 4; ++mt) {
#pragma unroll
    for (int ri = 0; ri < 4; ++ri) {
      const int rloc = w * 64 + mt * 16 + lk * 4 + ri;
      const float iv = invs[rloc];
      const long orow = R0 + rloc;
#pragma unroll
      for (int n4 = 0; n4 < 4; ++n4)
        ctx[orow * D + n4 * 16 + l15] = acc[mt][n4][ri] * iv;
    }
  }
}

extern "C" void kernel_launch(void* const* d_in, const int* in_sizes, int n_in,
                              void* d_out, int out_size, void* d_ws, size_t ws_size,
                              hipStream_t stream) {
  (void)in_sizes; (void)n_in; (void)out_size;
  const float* V = (const float*)d_in[2];           // Q,K provably unused (mask overwrites all scores)
  const int* mask = (const int*)d_in[3];
  float* ctx = (float*)d_out;                       // output 0: [B,H,S,D]
  float* attn = (float*)d_out + (size_t)CTX_ELEMS;  // output 1: [B,H,S,S]
  uint32_t* packed = (uint32_t*)d_out;              // scratch aliasing ctx region (tile-local)
  __bf16* VT = (__bf16*)d_ws;

  const int use_vt = (ws_size >= VT_BYTES) ? 1 : 0;
  k_mask<<<NVTB + NROWS, 256, 0, stream>>>(mask, V, attn, packed, VT, use_vt);
  if (use_vt)
    k_ctx<true><<<NROWS / BMC, 128, 0, stream>>>(packed, V, VT, ctx);
  else
    k_ctx<false><<<NROWS / BMC, 128, 0, stream>>>(packed, V, VT, ctx);
}

// Round 8
// 233.456 us; speedup vs baseline: 29.6901x; 1.0507x over previous
//
#include <hip/hip_runtime.h>
#include <hip/hip_bf16.h>
#include <stdint.h>

#define S 2048
#define D 64
#define BH 32
#define NROWS (BH * S)              // 65536
#define CTX_ELEMS (NROWS * D)
#define NVTB 512                    // VT rider blocks
#define NSTB 2048                   // stream blocks (grid-stride, 4 waves each)
#define VT_BYTES ((size_t)BH * 64 * 64 * 32 * 2)   // 8.4 MB tiled bf16 V^T

typedef __attribute__((ext_vector_type(8))) __bf16 bf16x8;
typedef __attribute__((ext_vector_type(4))) float f32x4;
typedef __attribute__((ext_vector_type(4))) int   i32x4;

// VT32 layout: VT32[bh][kk][c][k']  (kk=k/32, c=col 0..63, k'=k%32); B-frag for
// step kk = one bf16x8; a wave's 64 lanes cover a contiguous 1KB per n4-tile.

// ---------- Kernel 1: wave-per-row stream (sync-free) + VT riders ----------
// Lane l of a row owns elems {j*256 + l*4 + p : j=0..7, p=0..3} -> nibble word.
// cnt: popc + wave butterfly. attn: 8x f32x4 stores (1KB/instr). packed:
// lane l builds word l (k=[l*32,l*32+32)) via 8 shfl of nibble words.
__global__ __launch_bounds__(256) void k_mask(const int* __restrict__ mask,
                                              const float* __restrict__ V,
                                              float* __restrict__ attn,
                                              uint32_t* __restrict__ packed,
                                              __bf16* __restrict__ VT,
                                              int use_vt) {
  const int t = threadIdx.x;

  if (blockIdx.x < NVTB) {
    if (!use_vt) return;
    // ---- VT rider (R7-proven): bh = b>>4, kk in [(b&15)*4, +4) ----
    const int bh = blockIdx.x >> 4;
    const int kk0 = (blockIdx.x & 15) * 4;
    const int c = t >> 2;
    const int g = t & 3;
#pragma unroll
    for (int s = 0; s < 4; ++s) {
      const int kk = kk0 + s;
      const float* vp = V + ((long)bh * S + kk * 32 + g * 8) * D + c;
      bf16x8 o;
#pragma unroll
      for (int j = 0; j < 8; ++j) o[j] = (__bf16)vp[(long)j * D];
      *reinterpret_cast<bf16x8*>(VT + (((long)bh * 64 + kk) * 64 + c) * 32 + g * 8) = o;
    }
    return;
  }

  const int lane = t & 63;
  const int W = (blockIdx.x - NVTB) * 4 + (t >> 6);   // global wave id 0..8191

#pragma unroll 1
  for (int row = W; row < NROWS; row += NSTB * 4) {
    const int* mrow = mask + (long)row * S;

    uint32_t nib = 0;
#pragma unroll
    for (int j = 0; j < 8; ++j) {
      const i32x4 m = __builtin_nontemporal_load(
          (const i32x4*)(mrow + j * 256 + lane * 4));
      nib |= (m[0] == 0 ? 1u : 0u) << (j * 4);
      nib |= (m[1] == 0 ? 1u : 0u) << (j * 4 + 1);
      nib |= (m[2] == 0 ? 1u : 0u) << (j * 4 + 2);
      nib |= (m[3] == 0 ? 1u : 0u) << (j * 4 + 3);
    }

    int cnt = __popc(nib);
#pragma unroll
    for (int off = 1; off < 64; off <<= 1) cnt += __shfl_xor(cnt, off, 64);
    const float inv = (cnt > 0) ? (1.0f / (float)cnt) : 0.0f;

    float* arow = attn + (long)row * S;
#pragma unroll
    for (int j = 0; j < 8; ++j) {
      f32x4 a;
      a[0] = ((nib >> (j * 4)) & 1u)     ? inv : 0.0f;
      a[1] = ((nib >> (j * 4 + 1)) & 1u) ? inv : 0.0f;
      a[2] = ((nib >> (j * 4 + 2)) & 1u) ? inv : 0.0f;
      a[3] = ((nib >> (j * 4 + 3)) & 1u) ? inv : 0.0f;
      __builtin_nontemporal_store(a, (f32x4*)(arow + j * 256 + lane * 4));
    }

    // packed word l: bit i = elem k=l*32+i = nibble bit (i&3) of group (l>>3)
    // from lane (l&7)*8 + (i>>2)
    uint32_t word = 0;
    const int jsel = 4 * (lane >> 3);
    const int lbase = (lane & 7) * 8;
#pragma unroll
    for (int d = 0; d < 8; ++d) {
      const uint32_t nw = (uint32_t)__shfl((int)nib, lbase + d, 64);
      word |= ((nw >> jsel) & 0xFu) << (4 * d);
    }
    packed[(long)row * 64 + lane] = word;
  }
}

// ---------- Kernel 2: ctx = inv * (bits @ V), BMC=64 -> 1024 blocks ----------
// 2 waves; wave w rows [w*32,+32) (2 m-tiles), N=64. B-frags: 1KB contiguous
// wave loads from VT32 (or f32 gather fallback). 2-deep software pipeline.
#define BMC 64
template<bool USE_VT>
__global__ __launch_bounds__(128) void k_ctx(const uint32_t* __restrict__ packed,
                                             const float* __restrict__ V,
                                             const __bf16* __restrict__ VT,
                                             float* __restrict__ ctx) {
  // XCD swizzle: each XCD owns 4 whole (b,h) -> VT panel (256KB) L2-resident
  const int flat = blockIdx.x;
  const int wid = (flat & 7) * ((NROWS / BMC) / 8) + (flat >> 3);
  const int qt = wid & 31;
  const int bh = wid >> 5;

  const int t = threadIdx.x;
  const int lane = t & 63;
  const int w = t >> 6;               // wave 0..1, rows [w*32, w*32+32)
  const int l15 = lane & 15;
  const int lk = lane >> 4;           // 0..3

  __shared__ uint32_t pk[BMC * 65];   // byte stride 260 -> bank stride 1
  __shared__ float invs[BMC];

  const long R0 = (long)bh * S + (long)qt * BMC;

  for (int i = t; i < BMC * 64; i += 128)
    pk[(i >> 6) * 65 + (i & 63)] = packed[(R0 + (i >> 6)) * 64 + (i & 63)];
  __syncthreads();

  if (t < BMC) {
    int c = 0;
#pragma unroll
    for (int i = 0; i < 64; ++i) c += __popc(pk[t * 65 + i]);
    invs[t] = (c > 0) ? (1.0f / (float)c) : 0.0f;
  }
  __syncthreads();

  const uint8_t* pkb = (const uint8_t*)pk;
  const uint8_t* ap[2];
#pragma unroll
  for (int mt = 0; mt < 2; ++mt)
    ap[mt] = pkb + (w * 32 + mt * 16 + l15) * 260 + lk;
  const __bf16* vt0 = VT + ((long)bh * 64) * 64 * 32 + (long)l15 * 32 + lk * 8;
  const float* vf0 = V + (long)bh * S * D + (long)lk * 8 * D + l15;

  f32x4 acc[2][4];
#pragma unroll
  for (int a = 0; a < 2; ++a)
#pragma unroll
    for (int b = 0; b < 4; ++b) acc[a][b] = f32x4{0.f, 0.f, 0.f, 0.f};

  auto LOADB = [&](bf16x8* dst, uint32_t* by, int kk) {
    if (USE_VT) {
#pragma unroll
      for (int n4 = 0; n4 < 4; ++n4)
        dst[n4] = *reinterpret_cast<const bf16x8*>(vt0 + ((long)kk * 64 + n4 * 16) * 32);
    } else {
      const float* vp = vf0 + (long)kk * 32 * D;
#pragma unroll
      for (int n4 = 0; n4 < 4; ++n4) {
        bf16x8 x;
#pragma unroll
        for (int j = 0; j < 8; ++j) x[j] = (__bf16)vp[j * D + n4 * 16];
        dst[n4] = x;
      }
    }
#pragma unroll
    for (int mt = 0; mt < 2; ++mt) by[mt] = ap[mt][kk * 4];
  };

  auto COMPUTE = [&](const bf16x8* bf, const uint32_t* by) {
#pragma unroll
    for (int mt = 0; mt < 2; ++mt) {
      union { uint32_t u[4]; bf16x8 v; } am;
#pragma unroll
      for (int p = 0; p < 4; ++p) {
        am.u[p] = (((by[mt] >> (2 * p)) & 1u) ? 0x3F80u : 0u)
                | (((by[mt] >> (2 * p + 1)) & 1u) ? 0x3F800000u : 0u);
      }
#pragma unroll
      for (int n4 = 0; n4 < 4; ++n4)
        acc[mt][n4] = __builtin_amdgcn_mfma_f32_16x16x32_bf16(am.v, bf[n4], acc[mt][n4], 0, 0, 0);
    }
  };

  bf16x8 bA[4], bB[4];
  uint32_t byA[2], byB[2];
  LOADB(bA, byA, 0);
#pragma unroll 1
  for (int kk = 0; kk < S / 32; kk += 2) {
    LOADB(bB, byB, kk + 1);
    COMPUTE(bA, byA);
    if (kk + 2 < S / 32) LOADB(bA, byA, kk + 2);
    COMPUTE(bB, byB);
  }

  // epilogue: C/D layout col=l15, row=lk*4+ri (m89-verified)
#pragma unroll
  for (int mt = 0; mt < 2; ++mt) {
#pragma unroll
    for (int ri = 0; ri < 4; ++ri) {
      const int rloc = w * 32 + mt * 16 + lk * 4 + ri;
      const float iv = invs[rloc];
      const long orow = R0 + rloc;
#pragma unroll
      for (int n4 = 0; n4 < 4; ++n4)
        ctx[orow * D + n4 * 16 + l15] = acc[mt][n4][ri] * iv;
    }
  }
}

extern "C" void kernel_launch(void* const* d_in, const int* in_sizes, int n_in,
                              void* d_out, int out_size, void* d_ws, size_t ws_size,
                              hipStream_t stream) {
  (void)in_sizes; (void)n_in; (void)out_size;
  const float* V = (const float*)d_in[2];           // Q,K provably unused (mask overwrites all scores)
  const int* mask = (const int*)d_in[3];
  float* ctx = (float*)d_out;                       // output 0: [B,H,S,D]
  float* attn = (float*)d_out + (size_t)CTX_ELEMS;  // output 1: [B,H,S,S]
  uint32_t* packed = (uint32_t*)d_out;              // scratch aliasing ctx region (tile-local)
  __bf16* VT = (__bf16*)d_ws;

  const int use_vt = (ws_size >= VT_BYTES) ? 1 : 0;
  k_mask<<<NVTB + NSTB, 256, 0, stream>>>(mask, V, attn, packed, VT, use_vt);
  if (use_vt)
    k_ctx<true><<<NROWS / BMC, 128, 0, stream>>>(packed, V, VT, ctx);
  else
    k_ctx<false><<<NROWS / BMC, 128, 0, stream>>>(packed, V, VT, ctx);
}